// Round 7
// baseline (248.078 us; speedup 1.0000x reference)
//
#include <hip/hip_runtime.h>

// Problem constants (fixed by reference)
#define BB 16
#define CC 256
#define HH 100
#define WW 100
#define NN 100
#define RH 40
#define RW 40
#define KK 599   // num classes
#define TP 44    // tile row pitch (RW+4): keeps float4 LDS stores 16B-aligned

// out has BB*KK*CC = 2,453,504 floats = 613,376 float4 = 2396 blocks * 256
#define ZERO_BLOCKS 2396

// True vector type for __builtin_nontemporal_load (HIP's float4 is a struct,
// which the builtin rejects; an ext_vector_type compiles to the same
// global_load_dwordx4 with the nt bit set).
typedef float vfloat4 __attribute__((ext_vector_type(4)));

// Clear the whole output with coalesced float4 stores. With N=100 boxes per
// image, at most 100 of the 599 class rows per batch are nonzero; pool_kernel
// only overwrites those, everything else stays exactly 0 (matches reference).
__global__ __launch_bounds__(256) void zero_kernel(float4* __restrict__ out)
{
    out[(size_t)blockIdx.x * 256 + threadIdx.x] = make_float4(0.f, 0.f, 0.f, 0.f);
}

// Fused per-(b,c) kernel. Resize is register-blocked: 8 consecutive output
// pixels (one "col-group" g) consume exactly one ALIGNED 20-float window per
// input row: ox=8k+j -> ix0 = 20k + O[j], O = {0,3,5,8,10,13,15,18}, and the
// window base 20k is 16B-aligned. Each of 200 threads owns one (oy, g) task:
// 10 independent global_load_dwordx4 (both rows), lerp in registers, two
// float4 LDS stores. No staged LDS -> ~12 KB total.
//
// Feature loads are NON-TEMPORAL: each (b,c) plane is read by exactly one
// block, so there is zero cross-block reuse -- keeping the 131 MB stream out
// of L2 protects the shared boxes/cls lines and the partially-assembled
// sparse output lines from eviction.
__global__ __launch_bounds__(256) void pool_kernel(
    const float* __restrict__ feat, const float* __restrict__ boxes,
    const int* __restrict__ cls, float* __restrict__ out)
{
    __shared__ float tile[RH][TP];  // pitch 44: aligned f4 stores, scattered box reads
    __shared__ float sums[KK];
    __shared__ float cnts[KK];

    // XCD-chunked swizzle: consecutive c for one (b,k) output line share an
    // XCD's L2 so sparse 4B stores assemble into full 64B lines.
    const int raw = blockIdx.x;
    const int L = (raw & 7) * (BB * CC / 8) + (raw >> 3);  // bijective, 4096 blocks
    const int b = L >> 8;        // / 256
    const int c = L & 255;
    const int tid = threadIdx.x;

    // Early box/class loads (threads 0..99): latency hides under resize loads.
    // These ARE reused across the 256 blocks of a batch -> normal cacheable.
    float bx0 = 0.f, bx1 = 0.f, bx2 = 0.f, bx3 = 0.f;
    int myk = 0;
    if (tid < NN) {
        const float* bp = boxes + (size_t)(b * NN + tid) * 4;
        bx0 = bp[0]; bx1 = bp[1]; bx2 = bp[2]; bx3 = bp[3];
        myk = cls[b * NN + tid];
    }

    const float* __restrict__ src = feat + (size_t)(b * CC + c) * (HH * WW);

    // ---- phase 1a: issue all resize loads (10x dwordx4 per task thread) ----
    // Task tid < 200: oy = tid/5, col-group g = tid%5.
    // Rows: iy0 = (5*oy+1)>>1, iy0+1 (always interior).
    vfloat4 A0, A1, A2, A3, A4, B0, B1, B2, B3, B4;
    int oy = 0, g = 0;
    if (tid < 200) {
        oy = tid / 5;
        g = tid - oy * 5;
        int iy0 = (5 * oy + 1) >> 1;
        const vfloat4* p0 = reinterpret_cast<const vfloat4*>(src + iy0 * WW + g * 20);
        const vfloat4* p1 = reinterpret_cast<const vfloat4*>(src + (iy0 + 1) * WW + g * 20);
        A0 = __builtin_nontemporal_load(p0 + 0);
        A1 = __builtin_nontemporal_load(p0 + 1);
        A2 = __builtin_nontemporal_load(p0 + 2);
        A3 = __builtin_nontemporal_load(p0 + 3);
        A4 = __builtin_nontemporal_load(p0 + 4);
        B0 = __builtin_nontemporal_load(p1 + 0);
        B1 = __builtin_nontemporal_load(p1 + 1);
        B2 = __builtin_nontemporal_load(p1 + 2);
        B3 = __builtin_nontemporal_load(p1 + 3);
        B4 = __builtin_nontemporal_load(p1 + 4);
    }

    // ---- phase 1b: LDS init overlaps the in-flight global loads ----
    for (int k = tid; k < KK; k += 256) {
        sums[k] = 0.0f;
        cnts[k] = 0.0f;
    }

    // ---- phase 1c: consume loads, lerp, store tile row-segment ----
    if (tid < 200) {
        float w0[20] = { A0.x, A0.y, A0.z, A0.w, A1.x, A1.y, A1.z, A1.w,
                         A2.x, A2.y, A2.z, A2.w, A3.x, A3.y, A3.z, A3.w,
                         A4.x, A4.y, A4.z, A4.w };
        float w1[20] = { B0.x, B0.y, B0.z, B0.w, B1.x, B1.y, B1.z, B1.w,
                         B2.x, B2.y, B2.z, B2.w, B3.x, B3.y, B3.z, B3.w,
                         B4.x, B4.y, B4.z, B4.w };
        const int O[8] = { 0, 3, 5, 8, 10, 13, 15, 18 };
        float fy = (oy & 1) ? 0.25f : 0.75f;
        float res[8];
        #pragma unroll
        for (int j = 0; j < 8; ++j) {
            float fx = (j & 1) ? 0.25f : 0.75f;   // ox parity == j parity
            float top = (1.0f - fx) * w0[O[j]] + fx * w0[O[j] + 1];
            float bot = (1.0f - fx) * w1[O[j]] + fx * w1[O[j] + 1];
            res[j] = (1.0f - fy) * top + fy * bot;
        }
        float4* d4 = reinterpret_cast<float4*>(&tile[oy][g * 8]);
        d4[0] = make_float4(res[0], res[1], res[2], res[3]);
        d4[1] = make_float4(res[4], res[5], res[6], res[7]);
    }
    __syncthreads();

    // ---- phase 2: per-box pooling + class scatter (threads 0..99) ----
    if (tid < NN) {
        const float sc = 0.0390625f;  // 40/1024 = 5/128, exact
        // rintf -> v_rndne_f32: round half to even, matches jnp.round
        int x1 = (int)rintf(bx0 * sc);
        int y1 = (int)rintf(bx1 * sc);
        int x2 = (int)rintf(bx2 * sc);
        int y2 = (int)rintf(bx3 * sc);
        x1 = max(x1, 0); y1 = max(y1, 0);
        x2 = min(x2, RW); y2 = min(y2, RH);
        if (x1 < x2 && y1 < y2) {
            float s = 0.0f;
            for (int y = y1; y < y2; ++y)
                for (int x = x1; x < x2; ++x)
                    s += tile[y][x];
            float area = (float)((y2 - y1) * (x2 - x1));
            atomicAdd(&sums[myk], s / area);
            atomicAdd(&cnts[myk], 1.0f);
        }
    }
    __syncthreads();

    // ---- phase 3: sparse write of nonzero class means: out[b][k][c] ----
    float* o = out + (size_t)b * KK * CC + c;
    for (int k = tid; k < KK; k += 256) {
        float cn = cnts[k];
        if (cn > 0.0f) o[(size_t)k * CC] = sums[k] / cn;
    }
}

extern "C" void kernel_launch(void* const* d_in, const int* in_sizes, int n_in,
                              void* d_out, int out_size, void* d_ws, size_t ws_size,
                              hipStream_t stream) {
    (void)d_ws; (void)ws_size; (void)in_sizes; (void)n_in; (void)out_size;
    const float* feat  = (const float*)d_in[0];
    const float* boxes = (const float*)d_in[1];
    const int*   cls   = (const int*)d_in[2];
    float* out = (float*)d_out;

    zero_kernel<<<ZERO_BLOCKS, 256, 0, stream>>>((float4*)out);
    pool_kernel<<<BB * CC, 256, 0, stream>>>(feat, boxes, cls, out);
}

// Round 8
// 231.777 us; speedup vs baseline: 1.0703x; 1.0703x over previous
//
#include <hip/hip_runtime.h>

// Problem constants (fixed by reference)
#define BB 16
#define CC 256
#define HH 100
#define WW 100
#define NN 100
#define RH 40
#define RW 40
#define KK 599   // num classes
#define TP 44    // tile row pitch (RW+4): keeps float4 LDS stores 16B-aligned

// out has BB*KK*CC = 2,453,504 floats = 613,376 float4 = 2396 blocks * 256
#define ZERO_BLOCKS 2396

// Clear the whole output with coalesced float4 stores. With N=100 boxes per
// image, at most 100 of the 599 class rows per batch are nonzero; pool_kernel
// only overwrites those, everything else stays exactly 0 (matches reference).
__global__ __launch_bounds__(256) void zero_kernel(float4* __restrict__ out)
{
    out[(size_t)blockIdx.x * 256 + threadIdx.x] = make_float4(0.f, 0.f, 0.f, 0.f);
}

// Fused per-(b,c) kernel. Resize is register-blocked: 8 consecutive output
// pixels (one "col-group" g) consume exactly one ALIGNED 20-float window per
// input row: ox=8k+j -> ix0 = 20k + O[j], O = {0,3,5,8,10,13,15,18}, and the
// window base 20k is 16B-aligned. Each of 200 threads owns one (oy, g) task:
// 10 independent global_load_dwordx4 (both rows), lerp in registers, two
// float4 LDS stores. No staged LDS -> ~12 KB total, 8 blocks/CU.
//
// NOTE: non-temporal feature loads were tested (round 7) and REGRESSED
// 232.8 -> 248.1 us; plain cacheable loads are the measured optimum.
__global__ __launch_bounds__(256) void pool_kernel(
    const float* __restrict__ feat, const float* __restrict__ boxes,
    const int* __restrict__ cls, float* __restrict__ out)
{
    __shared__ float tile[RH][TP];  // pitch 44: aligned f4 stores, scattered box reads
    __shared__ float sums[KK];
    __shared__ float cnts[KK];

    // XCD-chunked swizzle: consecutive c for one (b,k) output line share an
    // XCD's L2 so sparse 4B stores assemble into full 64B lines.
    const int raw = blockIdx.x;
    const int L = (raw & 7) * (BB * CC / 8) + (raw >> 3);  // bijective, 4096 blocks
    const int b = L >> 8;        // / 256
    const int c = L & 255;
    const int tid = threadIdx.x;

    // Early box/class loads (threads 0..99): latency hides under resize loads.
    float bx0 = 0.f, bx1 = 0.f, bx2 = 0.f, bx3 = 0.f;
    int myk = 0;
    if (tid < NN) {
        const float* bp = boxes + (size_t)(b * NN + tid) * 4;
        bx0 = bp[0]; bx1 = bp[1]; bx2 = bp[2]; bx3 = bp[3];
        myk = cls[b * NN + tid];
    }

    const float* __restrict__ src = feat + (size_t)(b * CC + c) * (HH * WW);

    // ---- phase 1a: issue all resize loads (10x dwordx4 per task thread) ----
    // Task tid < 200: oy = tid/5, col-group g = tid%5.
    // Rows: iy0 = (5*oy+1)>>1, iy0+1 (always interior).
    float4 A0, A1, A2, A3, A4, B0, B1, B2, B3, B4;
    int oy = 0, g = 0;
    if (tid < 200) {
        oy = tid / 5;
        g = tid - oy * 5;
        int iy0 = (5 * oy + 1) >> 1;
        const float4* p0 = reinterpret_cast<const float4*>(src + iy0 * WW + g * 20);
        const float4* p1 = reinterpret_cast<const float4*>(src + (iy0 + 1) * WW + g * 20);
        A0 = p0[0]; A1 = p0[1]; A2 = p0[2]; A3 = p0[3]; A4 = p0[4];
        B0 = p1[0]; B1 = p1[1]; B2 = p1[2]; B3 = p1[3]; B4 = p1[4];
    }

    // ---- phase 1b: LDS init overlaps the in-flight global loads ----
    for (int k = tid; k < KK; k += 256) {
        sums[k] = 0.0f;
        cnts[k] = 0.0f;
    }

    // ---- phase 1c: consume loads, lerp, store tile row-segment ----
    if (tid < 200) {
        float w0[20] = { A0.x, A0.y, A0.z, A0.w, A1.x, A1.y, A1.z, A1.w,
                         A2.x, A2.y, A2.z, A2.w, A3.x, A3.y, A3.z, A3.w,
                         A4.x, A4.y, A4.z, A4.w };
        float w1[20] = { B0.x, B0.y, B0.z, B0.w, B1.x, B1.y, B1.z, B1.w,
                         B2.x, B2.y, B2.z, B2.w, B3.x, B3.y, B3.z, B3.w,
                         B4.x, B4.y, B4.z, B4.w };
        const int O[8] = { 0, 3, 5, 8, 10, 13, 15, 18 };
        float fy = (oy & 1) ? 0.25f : 0.75f;
        float res[8];
        #pragma unroll
        for (int j = 0; j < 8; ++j) {
            float fx = (j & 1) ? 0.25f : 0.75f;   // ox parity == j parity
            float top = (1.0f - fx) * w0[O[j]] + fx * w0[O[j] + 1];
            float bot = (1.0f - fx) * w1[O[j]] + fx * w1[O[j] + 1];
            res[j] = (1.0f - fy) * top + fy * bot;
        }
        float4* d4 = reinterpret_cast<float4*>(&tile[oy][g * 8]);
        d4[0] = make_float4(res[0], res[1], res[2], res[3]);
        d4[1] = make_float4(res[4], res[5], res[6], res[7]);
    }
    __syncthreads();

    // ---- phase 2: per-box pooling + class scatter (threads 0..99) ----
    if (tid < NN) {
        const float sc = 0.0390625f;  // 40/1024 = 5/128, exact
        // rintf -> v_rndne_f32: round half to even, matches jnp.round
        int x1 = (int)rintf(bx0 * sc);
        int y1 = (int)rintf(bx1 * sc);
        int x2 = (int)rintf(bx2 * sc);
        int y2 = (int)rintf(bx3 * sc);
        x1 = max(x1, 0); y1 = max(y1, 0);
        x2 = min(x2, RW); y2 = min(y2, RH);
        if (x1 < x2 && y1 < y2) {
            float s = 0.0f;
            for (int y = y1; y < y2; ++y)
                for (int x = x1; x < x2; ++x)
                    s += tile[y][x];
            float area = (float)((y2 - y1) * (x2 - x1));
            atomicAdd(&sums[myk], s / area);
            atomicAdd(&cnts[myk], 1.0f);
        }
    }
    __syncthreads();

    // ---- phase 3: sparse write of nonzero class means: out[b][k][c] ----
    float* o = out + (size_t)b * KK * CC + c;
    for (int k = tid; k < KK; k += 256) {
        float cn = cnts[k];
        if (cn > 0.0f) o[(size_t)k * CC] = sums[k] / cn;
    }
}

extern "C" void kernel_launch(void* const* d_in, const int* in_sizes, int n_in,
                              void* d_out, int out_size, void* d_ws, size_t ws_size,
                              hipStream_t stream) {
    (void)d_ws; (void)ws_size; (void)in_sizes; (void)n_in; (void)out_size;
    const float* feat  = (const float*)d_in[0];
    const float* boxes = (const float*)d_in[1];
    const int*   cls   = (const int*)d_in[2];
    float* out = (float*)d_out;

    zero_kernel<<<ZERO_BLOCKS, 256, 0, stream>>>((float4*)out);
    pool_kernel<<<BB * CC, 256, 0, stream>>>(feat, boxes, cls, out);
}